// Round 1
// baseline (182.134 us; speedup 1.0000x reference)
//
#include <hip/hip_runtime.h>
#include <hip/hip_bf16.h>

#define N_NODES 8192
#define DIM 128
#define MASK_THRESH 0.8f

using f32x4  = __attribute__((ext_vector_type(4))) float;
using bf16x8 = __attribute__((ext_vector_type(8))) short;

// round-to-nearest-even f32 -> bf16 bits
static __device__ __forceinline__ short f2bf(float f) {
    unsigned u = __builtin_bit_cast(unsigned, f);
    u += 0x7fffu + ((u >> 16) & 1u);
    return (short)(u >> 16);
}

// ---------------------------------------------------------------------------
// Kernel 1: Vt[d][j] = dot(X[j,:], W[d,:]) + b[d], stored bf16, Vt is [128][8192]
// (transposed so kernel 2's B-fragment reads are contiguous 16B per lane)
// ---------------------------------------------------------------------------
__global__ __launch_bounds__(256) void build_vt_kernel(
    const float* __restrict__ X, const float* __restrict__ W,
    const float* __restrict__ bias, short* __restrict__ Vt) {
    __shared__ float xs[32][128];
    const int jt = blockIdx.x * 32;
    for (int e = threadIdx.x; e < 32 * 128; e += 256) {
        xs[e >> 7][e & 127] = X[(size_t)(jt + (e >> 7)) * DIM + (e & 127)];
    }
    __syncthreads();
    const int d  = threadIdx.x & 127;
    const int jh = threadIdx.x >> 7;   // 0 or 1: which 16-row half
    float bv = bias[d];
    float acc[16];
#pragma unroll
    for (int i = 0; i < 16; i++) acc[i] = bv;
    const float* wrow = W + (size_t)d * DIM;
    for (int k = 0; k < DIM; k += 4) {
        f32x4 wv = *(const f32x4*)(wrow + k);
#pragma unroll
        for (int i = 0; i < 16; i++) {
            f32x4 xv = *(const f32x4*)(&xs[jh * 16 + i][k]);
            acc[i] += xv[0] * wv[0] + xv[1] * wv[1] + xv[2] * wv[2] + xv[3] * wv[3];
        }
    }
    bf16x8 o0, o1;
#pragma unroll
    for (int i = 0; i < 8; i++) { o0[i] = f2bf(acc[i]); o1[i] = f2bf(acc[8 + i]); }
    short* dst = Vt + (size_t)d * N_NODES + jt + jh * 16;
    *(bf16x8*)(dst)     = o0;
    *(bf16x8*)(dst + 8) = o1;
}

// ---------------------------------------------------------------------------
// Kernel 2: fused masked-softmax(A) @ V, leaky_relu, single pass over A.
//   block = 512 threads (8 waves), handles 16 output rows x 128 cols.
//   wave w covers K-chunk [w*1024, (w+1)*1024); LDS 2-stage reduction.
//   Softmax shift-free: logits in (0.8,1], p = (a>0.8)? exp(a) : 0.
// ---------------------------------------------------------------------------
__global__ __launch_bounds__(512, 4) void fused_softmax_pv_kernel(
    const float* __restrict__ A, const short* __restrict__ Vt,
    float* __restrict__ out) {
    __shared__ float accs[4][16][132];   // padded stride vs bank conflicts
    __shared__ float zs[8][16];

    const int tid   = threadIdx.x;
    const int wid   = tid >> 6;
    const int lane  = tid & 63;
    const int row_a = lane & 15;     // A-frag row / B-frag col / D col
    const int kg    = lane >> 4;     // k-group (0..3), 8 k each
    const int r0    = blockIdx.x * 16;

    f32x4 acc[8];
#pragma unroll
    for (int t = 0; t < 8; t++) acc[t] = (f32x4)0.0f;
    float zacc = 0.0f;

    const float* aptr = A + (size_t)(r0 + row_a) * N_NODES + (size_t)wid * 1024 + kg * 8;
    const short* bbase = Vt + (size_t)row_a * N_NODES + (size_t)wid * 1024 + kg * 8;

    for (int ks = 0; ks < 1024; ks += 32) {
        f32x4 a0 = *(const f32x4*)(aptr + ks);
        f32x4 a1 = *(const f32x4*)(aptr + ks + 4);
        float p[8];
#pragma unroll
        for (int i = 0; i < 4; i++) {
            p[i]     = (a0[i] > MASK_THRESH) ? __expf(a0[i]) : 0.0f;
            p[i + 4] = (a1[i] > MASK_THRESH) ? __expf(a1[i]) : 0.0f;
        }
        bf16x8 af;
#pragma unroll
        for (int i = 0; i < 8; i++) { zacc += p[i]; af[i] = f2bf(p[i]); }
#pragma unroll
        for (int t = 0; t < 8; t++) {
            bf16x8 bf = *(const bf16x8*)(bbase + (size_t)t * 16 * N_NODES + ks);
            acc[t] = __builtin_amdgcn_mfma_f32_16x16x32_bf16(af, bf, acc[t], 0, 0, 0);
        }
    }

    // Z: sum the 4 k-groups for each row (lanes r, r+16, r+32, r+48)
    zacc += __shfl_xor(zacc, 16);
    zacc += __shfl_xor(zacc, 32);
    if (lane < 16) zs[wid][lane] = zacc;   // lane == row for lane<16

    // stage 1: waves 0-3 write their partial tiles
    if (wid < 4) {
#pragma unroll
        for (int t = 0; t < 8; t++)
#pragma unroll
            for (int r = 0; r < 4; r++)
                accs[wid][kg * 4 + r][t * 16 + row_a] = acc[t][r];
    }
    __syncthreads();
    // stage 2: waves 4-7 accumulate into them (disjoint buffers, no race)
    if (wid >= 4) {
#pragma unroll
        for (int t = 0; t < 8; t++)
#pragma unroll
            for (int r = 0; r < 4; r++)
                accs[wid - 4][kg * 4 + r][t * 16 + row_a] += acc[t][r];
    }
    __syncthreads();

    // final: sum 4 buffers, normalize by Z, leaky_relu, write
    for (int e = tid; e < 16 * 128; e += 512) {
        const int row = e >> 7;
        const int col = e & 127;
        float s = 0.0f, zt = 0.0f;
#pragma unroll
        for (int w = 0; w < 4; w++) s += accs[w][row][col];
#pragma unroll
        for (int w = 0; w < 8; w++) zt += zs[w][row];
        float v = s / zt;
        out[(size_t)(r0 + row) * DIM + col] = (v > 0.0f) ? v : 0.01f * v;
    }
}

extern "C" void kernel_launch(void* const* d_in, const int* in_sizes, int n_in,
                              void* d_out, int out_size, void* d_ws, size_t ws_size,
                              hipStream_t stream) {
    const float* A = (const float*)d_in[0];
    const float* X = (const float*)d_in[1];
    const float* W = (const float*)d_in[2];
    const float* b = (const float*)d_in[3];
    float* out = (float*)d_out;
    short* Vt  = (short*)d_ws;   // 128*8192 bf16 = 2 MiB scratch

    build_vt_kernel<<<N_NODES / 32, 256, 0, stream>>>(X, W, b, Vt);
    fused_softmax_pv_kernel<<<N_NODES / 16, 512, 0, stream>>>(A, Vt, out);
}